// Round 1
// baseline (1133.013 us; speedup 1.0000x reference)
//
#include <hip/hip_runtime.h>

#define BB 256
#define LL 512
#define DD 768
#define CC 19
#define IMPOSSIBLE -10000.0f

__global__ __launch_bounds__(256) void crf_fused(
    const float* __restrict__ feats,   // [B][L][D]
    const float* __restrict__ masks,   // [B][L]
    const float* __restrict__ W,       // [C][D]
    const float* __restrict__ bias,    // [C]
    const float* __restrict__ trans,   // [C][C]
    float* __restrict__ out)           // [B] scores ++ [B][L] paths (as float)
{
    __shared__ float elds[LL * CC];           // emissions for this batch: 38912 B
    __shared__ float mlds[LL];                // masks: 2048 B
    __shared__ unsigned char bp8[LL * 20];    // backpointers, stride 20: 10240 B
    __shared__ float fbuf[CC];

    const int tid = threadIdx.x;
    const int b  = blockIdx.x;

    // stage masks for this batch
    mlds[tid]       = masks[b * LL + tid];
    mlds[tid + 256] = masks[b * LL + tid + 256];

    // ---------------- emission GEMM phase ----------------
    // thread handles rows tid and tid+256 of this batch; acc[19] in regs;
    // W addresses are wave-uniform -> s_load, L2-hot.
    for (int pass = 0; pass < 2; ++pass) {
        const int r = pass * 256 + tid;
        const float4* fv =
            reinterpret_cast<const float4*>(feats + ((size_t)b * LL + r) * DD);
        float acc[CC];
#pragma unroll
        for (int c = 0; c < CC; ++c) acc[c] = bias[c];

        for (int kc = 0; kc < DD / 16; ++kc) {
            float4 a0 = fv[kc * 4 + 0];
            float4 a1 = fv[kc * 4 + 1];
            float4 a2 = fv[kc * 4 + 2];
            float4 a3 = fv[kc * 4 + 3];
#pragma unroll
            for (int c = 0; c < CC; ++c) {
                const float4* wv =
                    reinterpret_cast<const float4*>(W + c * DD) + kc * 4;
                float4 w0 = wv[0], w1 = wv[1], w2 = wv[2], w3 = wv[3];
                float d0 = a0.x * w0.x + a0.y * w0.y + a0.z * w0.z + a0.w * w0.w;
                float d1 = a1.x * w1.x + a1.y * w1.y + a1.z * w1.z + a1.w * w1.w;
                float d2 = a2.x * w2.x + a2.y * w2.y + a2.z * w2.z + a2.w * w2.w;
                float d3 = a3.x * w3.x + a3.y * w3.y + a3.z * w3.z + a3.w * w3.w;
                acc[c] += (d0 + d1) + (d2 + d3);
            }
        }
#pragma unroll
        for (int c = 0; c < CC; ++c) elds[r * CC + c] = acc[c];
    }
    __syncthreads();
    if (tid >= 64) return;   // only wave 0 continues; no more barriers below

    // ---------------- Viterbi scan (wave 0, lane = class) ----------------
    const int lane = tid;
    const int ccl  = (lane < CC) ? lane : (CC - 1);
    float T[CC];
#pragma unroll
    for (int p = 0; p < CC; ++p) T[p] = trans[ccl * CC + p];
    const float Tstop = trans[(CC - 1) * CC + ccl];

    float s = (lane == CC - 2) ? 0.0f : IMPOSSIBLE;   // start state = C-2

    for (int t = 0; t < LL; ++t) {
        float cand[CC];
#pragma unroll
        for (int p = 0; p < CC; ++p) {
            int spi = __builtin_amdgcn_readlane(__builtin_bit_cast(int, s), p);
            cand[p] = __builtin_bit_cast(float, spi) + T[p];
        }
        float mx = cand[0];
#pragma unroll
        for (int p = 1; p < CC; ++p) mx = fmaxf(mx, cand[p]);
        int arg = CC - 1;
#pragma unroll
        for (int p = CC - 2; p >= 0; --p) arg = (cand[p] == mx) ? p : arg;  // first-index tie

        float e = elds[t * CC + ccl];
        float m = mlds[t];
        float a = mx + e;
        s = a * m + s * (1.0f - m);   // exact replica of reference blend
        if (lane < CC) bp8[t * 20 + lane] = (unsigned char)arg;
    }

    float fin = s + Tstop;
    if (lane < CC) fbuf[lane] = fin;

    // ---------------- argmax over classes + backtrack (lane 0) ----------------
    if (lane == 0) {
        float best = fbuf[0];
        int   btag = 0;
#pragma unroll
        for (int c = 1; c < CC; ++c) {
            float v = fbuf[c];
            if (v > best) { best = v; btag = c; }   // strict > keeps first index
        }
        out[b] = best;

        float* pout = out + BB + (size_t)b * LL;
        int cur = btag;
        for (int t = LL - 1; t >= 0; --t) {
            float m = mlds[t];
            bool valid = (m > 0.0f);
            pout[t] = (float)(valid ? cur : -1);
            int nxt = bp8[t * 20 + cur];
            cur = valid ? nxt : cur;
        }
    }
}

extern "C" void kernel_launch(void* const* d_in, const int* in_sizes, int n_in,
                              void* d_out, int out_size, void* d_ws, size_t ws_size,
                              hipStream_t stream) {
    const float* feats = (const float*)d_in[0];
    const float* masks = (const float*)d_in[1];
    const float* W     = (const float*)d_in[2];
    const float* bias  = (const float*)d_in[3];
    const float* trans = (const float*)d_in[4];
    float* out = (float*)d_out;

    crf_fused<<<dim3(BB), dim3(256), 0, stream>>>(feats, masks, W, bias, trans, out);
}

// Round 2
// 921.190 us; speedup vs baseline: 1.2299x; 1.2299x over previous
//
#include <hip/hip_runtime.h>

#define BB 256
#define LL 512
#define DD 768
#define CC 19
#define ES 20            // padded class stride (16B-aligned rows, breaks pow2 strides)
#define IMPOSSIBLE -10000.0f

__global__ __launch_bounds__(512) void crf_fused(
    const float* __restrict__ feats,   // [B][L][D]
    const float* __restrict__ masks,   // [B][L]
    const float* __restrict__ W,       // [C][D]
    const float* __restrict__ bias,    // [C]
    const float* __restrict__ trans,   // [C][C]
    float* __restrict__ out)           // [B] scores ++ [B][L] paths (as float)
{
    __shared__ float elds[LL * ES];           // 40960 B  emissions
    __shared__ float mlds[LL];                //  2048 B  masks
    __shared__ unsigned char bp8[LL * ES];    // 10240 B  backpointers
    __shared__ float fbuf[CC];

    const int tid = threadIdx.x;
    const int b   = blockIdx.x;

    mlds[tid] = masks[b * LL + tid];          // 512 threads == LL

    // ---------------- emission GEMM: thread tid -> row tid ----------------
    {
        const float4* fv =
            reinterpret_cast<const float4*>(feats + ((size_t)b * LL + tid) * DD);
        float acc[ES];
#pragma unroll
        for (int c = 0; c < CC; ++c) acc[c] = bias[c];
        acc[19] = 0.0f;

        // software pipeline: 64B of this row in flight one kc ahead
        float4 a0 = fv[0], a1 = fv[1], a2 = fv[2], a3 = fv[3];
        for (int kc = 0; kc < DD / 16; ++kc) {
            const int nk = (kc < DD / 16 - 1) ? kc + 1 : kc;   // clamp (no OOB)
            float4 n0 = fv[nk * 4 + 0];
            float4 n1 = fv[nk * 4 + 1];
            float4 n2 = fv[nk * 4 + 2];
            float4 n3 = fv[nk * 4 + 3];
#pragma unroll
            for (int c = 0; c < CC; ++c) {
                const float4* wv =
                    reinterpret_cast<const float4*>(W + c * DD + kc * 16);
                float4 w0 = wv[0], w1 = wv[1], w2 = wv[2], w3 = wv[3];
                float d0 = a0.x * w0.x + a0.y * w0.y + a0.z * w0.z + a0.w * w0.w;
                float d1 = a1.x * w1.x + a1.y * w1.y + a1.z * w1.z + a1.w * w1.w;
                float d2 = a2.x * w2.x + a2.y * w2.y + a2.z * w2.z + a2.w * w2.w;
                float d3 = a3.x * w3.x + a3.y * w3.y + a3.z * w3.z + a3.w * w3.w;
                acc[c] += (d0 + d1) + (d2 + d3);
            }
            a0 = n0; a1 = n1; a2 = n2; a3 = n3;
        }
        // vectorized LDS store: 5 x ds_write_b128 (stride 20 floats = 80 B, aligned)
        float4* ed = reinterpret_cast<float4*>(&elds[tid * ES]);
#pragma unroll
        for (int q = 0; q < 5; ++q)
            ed[q] = make_float4(acc[4 * q + 0], acc[4 * q + 1],
                                acc[4 * q + 2], acc[4 * q + 3]);
    }
    __syncthreads();
    if (tid >= 64) return;      // wave 0 only below; no more barriers

    // ---------------- Viterbi scan (lane = class) ----------------
    const int lane = tid;
    const int ccl  = (lane < CC) ? lane : (CC - 1);
    float T[CC];
#pragma unroll
    for (int p = 0; p < CC; ++p) T[p] = trans[ccl * CC + p];
    const float Tstop = trans[(CC - 1) * CC + ccl];

    float s = (lane == CC - 2) ? 0.0f : IMPOSSIBLE;

    float e = elds[ccl];        // t = 0 prefetch
    float m = mlds[0];
    for (int t = 0; t < LL; ++t) {
        const int tn = (t < LL - 1) ? t + 1 : t;
        float e_n = elds[tn * ES + ccl];        // prefetch next step
        float m_n = mlds[tn];

        float cand[CC];
#pragma unroll
        for (int p = 0; p < CC; ++p) {
            int spi = __builtin_amdgcn_readlane(__builtin_bit_cast(int, s), p);
            cand[p] = __builtin_bit_cast(float, spi) + T[p];
        }
        // depth-3 max tree (v_max3)
        float t0 = fmaxf(fmaxf(cand[0],  cand[1]),  cand[2]);
        float t1 = fmaxf(fmaxf(cand[3],  cand[4]),  cand[5]);
        float t2 = fmaxf(fmaxf(cand[6],  cand[7]),  cand[8]);
        float t3 = fmaxf(fmaxf(cand[9],  cand[10]), cand[11]);
        float t4 = fmaxf(fmaxf(cand[12], cand[13]), cand[14]);
        float t5 = fmaxf(fmaxf(cand[15], cand[16]), cand[17]);
        float u0 = fmaxf(fmaxf(t0, t1), t2);
        float u1 = fmaxf(fmaxf(t3, t4), t5);
        float mx = fmaxf(fmaxf(u0, u1), cand[18]);

        int arg = CC - 1;
#pragma unroll
        for (int p = CC - 2; p >= 0; --p) arg = (cand[p] == mx) ? p : arg; // first idx

        float a = mx + e;
        s = a * m + s * (1.0f - m);             // exact reference blend
        if (lane < CC) bp8[t * ES + lane] = (unsigned char)arg;

        e = e_n; m = m_n;
    }

    float fin = s + Tstop;
    if (lane < CC) fbuf[lane] = fin;

    // ---------------- final argmax + backtrack (lane 0) ----------------
    if (lane == 0) {
        float best = fbuf[0];
        int   btag = 0;
#pragma unroll
        for (int c = 1; c < CC; ++c) {
            float v = fbuf[c];
            if (v > best) { best = v; btag = c; }
        }
        out[b] = best;

        float* pout = out + BB + (size_t)b * LL;
        int cur = btag;
        for (int t = LL - 1; t >= 0; --t) {
            float mm = mlds[t];
            bool valid = (mm > 0.0f);
            pout[t] = (float)(valid ? cur : -1);
            int nxt = bp8[t * ES + cur];
            cur = valid ? nxt : cur;
        }
    }
}

extern "C" void kernel_launch(void* const* d_in, const int* in_sizes, int n_in,
                              void* d_out, int out_size, void* d_ws, size_t ws_size,
                              hipStream_t stream) {
    const float* feats = (const float*)d_in[0];
    const float* masks = (const float*)d_in[1];
    const float* W     = (const float*)d_in[2];
    const float* bias  = (const float*)d_in[3];
    const float* trans = (const float*)d_in[4];
    float* out = (float*)d_out;

    crf_fused<<<dim3(BB), dim3(512), 0, stream>>>(feats, masks, W, bias, trans, out);
}

// Round 3
// 726.208 us; speedup vs baseline: 1.5602x; 1.2685x over previous
//
#include <hip/hip_runtime.h>

#define BB 256
#define LL 512
#define DD 768
#define CC 19
#define ES 20            // padded class stride
#define IMPOSSIBLE -10000.0f

// ---------------------------------------------------------------------------
// Kernel 1: emissions GEMM.  emis[row][c] = feats[row]·W[c] + bias[c]
// 512 blocks x 256 threads, one row per thread. W lives in LDS; per-(kc,c)
// reads are wave-uniform same-address broadcasts (conflict-free).
// ---------------------------------------------------------------------------
__global__ __launch_bounds__(256) void emis_gemm(
    const float* __restrict__ feats,   // [B*L][D]
    const float* __restrict__ W,       // [C][D]
    const float* __restrict__ bias,    // [C]
    float* __restrict__ emis)          // [B*L][ES]
{
    __shared__ float Wl[CC * DD];      // 58368 B
    const int tid = threadIdx.x;

    // cooperative W load: 14592 floats = 57 * 256, coalesced
#pragma unroll
    for (int i = 0; i < 57; ++i)
        Wl[i * 256 + tid] = W[i * 256 + tid];
    __syncthreads();

    const int row = blockIdx.x * 256 + tid;
    const float4* fv = reinterpret_cast<const float4*>(feats + (size_t)row * DD);

    float acc[ES];
#pragma unroll
    for (int c = 0; c < CC; ++c) acc[c] = bias[c];
    acc[19] = 0.0f;

    float4 a0 = fv[0], a1 = fv[1], a2 = fv[2], a3 = fv[3];
    for (int kc = 0; kc < DD / 16; ++kc) {
        const int nk = (kc < DD / 16 - 1) ? kc + 1 : kc;
        float4 n0 = fv[nk * 4 + 0];
        float4 n1 = fv[nk * 4 + 1];
        float4 n2 = fv[nk * 4 + 2];
        float4 n3 = fv[nk * 4 + 3];
#pragma unroll
        for (int c = 0; c < CC; ++c) {
            const float4* wv = reinterpret_cast<const float4*>(&Wl[c * DD + kc * 16]);
            float4 w0 = wv[0], w1 = wv[1], w2 = wv[2], w3 = wv[3];
            float d0 = a0.x * w0.x + a0.y * w0.y + a0.z * w0.z + a0.w * w0.w;
            float d1 = a1.x * w1.x + a1.y * w1.y + a1.z * w1.z + a1.w * w1.w;
            float d2 = a2.x * w2.x + a2.y * w2.y + a2.z * w2.z + a2.w * w2.w;
            float d3 = a3.x * w3.x + a3.y * w3.y + a3.z * w3.z + a3.w * w3.w;
            acc[c] += (d0 + d1) + (d2 + d3);
        }
        a0 = n0; a1 = n1; a2 = n2; a3 = n3;
    }

    float4* ed = reinterpret_cast<float4*>(emis + (size_t)row * ES);
#pragma unroll
    for (int q = 0; q < 5; ++q)
        ed[q] = make_float4(acc[4 * q + 0], acc[4 * q + 1],
                            acc[4 * q + 2], acc[4 * q + 3]);
}

// ---------------------------------------------------------------------------
// Kernel 2: Viterbi scan + parallel backtrack.  256 blocks x 64 threads
// (one wave per batch).  lane = class for the scan; segment-parallel
// function-composition backtrack (64 segments x 8 steps).
// ---------------------------------------------------------------------------
__global__ __launch_bounds__(64) void scan_bt(
    const float* __restrict__ emis,    // [B*L][ES]
    const float* __restrict__ masks,   // [B][L]
    const float* __restrict__ trans,   // [C][C]
    float* __restrict__ out)           // [B] ++ [B][L]
{
    __shared__ float elds[LL * ES];            // 40960 B
    __shared__ float mlds[LL];                 //  2048 B
    __shared__ unsigned char bp8[LL * ES];     // 10240 B
    __shared__ unsigned char Hl[64 * ES];      //  1280 B
    __shared__ unsigned char vseg[64];
    __shared__ float fbuf[CC];

    const int lane = threadIdx.x;
    const int b    = blockIdx.x;

    // stage emissions (512*20 floats = 2560 float4) and masks, coalesced
    {
        const float4* src = reinterpret_cast<const float4*>(emis + (size_t)b * LL * ES);
        float4* dst = reinterpret_cast<float4*>(elds);
#pragma unroll
        for (int i = 0; i < 40; ++i) dst[i * 64 + lane] = src[i * 64 + lane];
        const float4* ms = reinterpret_cast<const float4*>(masks + b * LL);
        float4* md = reinterpret_cast<float4*>(mlds);
        md[lane] = ms[lane];
        md[64 + lane] = ms[64 + lane];
    }
    __syncthreads();

    // ---------------- scan: lane = class ----------------
    const int ccl = (lane < CC) ? lane : (CC - 1);
    float T[CC];
#pragma unroll
    for (int p = 0; p < CC; ++p) T[p] = trans[ccl * CC + p];
    const float Tstop = trans[(CC - 1) * CC + ccl];

    float s = (lane == CC - 2) ? 0.0f : IMPOSSIBLE;

    float e = elds[ccl];
    float m = mlds[0];
    for (int t = 0; t < LL; ++t) {
        const int tn = (t < LL - 1) ? t + 1 : t;
        float e_n = elds[tn * ES + ccl];
        float m_n = mlds[tn];

        float cand[CC];
#pragma unroll
        for (int p = 0; p < CC; ++p) {
            int spi = __builtin_amdgcn_readlane(__builtin_bit_cast(int, s), p);
            cand[p] = __builtin_bit_cast(float, spi) + T[p];
        }
        float t0 = fmaxf(fmaxf(cand[0],  cand[1]),  cand[2]);
        float t1 = fmaxf(fmaxf(cand[3],  cand[4]),  cand[5]);
        float t2 = fmaxf(fmaxf(cand[6],  cand[7]),  cand[8]);
        float t3 = fmaxf(fmaxf(cand[9],  cand[10]), cand[11]);
        float t4 = fmaxf(fmaxf(cand[12], cand[13]), cand[14]);
        float t5 = fmaxf(fmaxf(cand[15], cand[16]), cand[17]);
        float u0 = fmaxf(fmaxf(t0, t1), t2);
        float u1 = fmaxf(fmaxf(t3, t4), t5);
        float mx = fmaxf(fmaxf(u0, u1), cand[18]);

        int arg = CC - 1;
#pragma unroll
        for (int p = CC - 2; p >= 0; --p) arg = (cand[p] == mx) ? p : arg;

        float a = mx + e;
        s = a * m + s * (1.0f - m);
        if (lane < CC) bp8[t * ES + lane] = (unsigned char)arg;

        e = e_n; m = m_n;
    }

    float fin = s + Tstop;
    if (lane < CC) fbuf[lane] = fin;
    __syncthreads();

    // ---------------- final argmax (redundant on all lanes) ----------------
    float best = fbuf[0];
    int   btag = 0;
#pragma unroll
    for (int c = 1; c < CC; ++c) {
        float v = fbuf[c];
        if (v > best) { best = v; btag = c; }
    }
    if (lane == 0) out[b] = best;

    // ---------------- segment transfer tables: lane i covers t in [i*8, i*8+8) ----
    {
        const int base = lane * 8;
        float mj[8];
#pragma unroll
        for (int j = 0; j < 8; ++j) mj[j] = mlds[base + j];
#pragma unroll
        for (int c = 0; c < CC; ++c) {
            int x = c;
#pragma unroll
            for (int j = 7; j >= 0; --j) {
                int nx = bp8[(base + j) * ES + x];
                x = (mj[j] > 0.0f) ? nx : x;
            }
            Hl[lane * ES + c] = (unsigned char)x;
        }
    }
    __syncthreads();

    // ---------------- scalar chain of segment-entry values ----------------
    if (lane == 0) {
        int v = btag;
        vseg[63] = (unsigned char)v;
        for (int i = 62; i >= 0; --i) {
            v = Hl[(i + 1) * ES + v];
            vseg[i] = (unsigned char)v;
        }
    }
    __syncthreads();

    // ---------------- fill 8 tags per lane, store as 2x float4 ----------------
    {
        const int base = lane * 8;
        int cur = vseg[lane];
        float tg[8];
#pragma unroll
        for (int j = 7; j >= 0; --j) {
            bool valid = mlds[base + j] > 0.0f;
            tg[j] = (float)(valid ? cur : -1);
            int nx = bp8[(base + j) * ES + cur];
            cur = valid ? nx : cur;
        }
        float4* pout = reinterpret_cast<float4*>(out + BB + (size_t)b * LL + base);
        pout[0] = make_float4(tg[0], tg[1], tg[2], tg[3]);
        pout[1] = make_float4(tg[4], tg[5], tg[6], tg[7]);
    }
}

extern "C" void kernel_launch(void* const* d_in, const int* in_sizes, int n_in,
                              void* d_out, int out_size, void* d_ws, size_t ws_size,
                              hipStream_t stream) {
    const float* feats = (const float*)d_in[0];
    const float* masks = (const float*)d_in[1];
    const float* W     = (const float*)d_in[2];
    const float* bias  = (const float*)d_in[3];
    const float* trans = (const float*)d_in[4];
    float* out  = (float*)d_out;
    float* emis = (float*)d_ws;        // 131072 * 20 * 4 = 10.5 MB scratch

    emis_gemm<<<dim3(512), dim3(256), 0, stream>>>(feats, W, bias, emis);
    scan_bt<<<dim3(BB), dim3(64), 0, stream>>>(emis, masks, trans, out);
}